// Round 1
// baseline (1696.707 us; speedup 1.0000x reference)
//
#include <hip/hip_runtime.h>

typedef unsigned short u16;
typedef unsigned int u32;
typedef short bf16x8 __attribute__((ext_vector_type(8)));
typedef float f32x4 __attribute__((ext_vector_type(4)));

static constexpr int LS = 2048;   // seq len
static constexpr int DM = 1024;   // d_model
static constexpr int DI = 2048;   // d_inner
static constexpr int DSn = 16;    // d_state
static constexpr int DTRk = 64;   // dt_rank
static constexpr int MR = 4096;   // B*L rows

#define DEV __device__ __forceinline__

DEV u16 f2bf(float f) {
  u32 u = __float_as_uint(f);
  u32 r = (u + 0x7FFF + ((u >> 16) & 1)) >> 16;
  return (u16)r;
}
DEV float bf2f(u16 h) { return __uint_as_float(((u32)h) << 16); }

DEV void gload16(const u16* g, u16* l) {
  __builtin_amdgcn_global_load_lds((const __attribute__((address_space(1))) u32*)g,
                                   (__attribute__((address_space(3))) u32*)l, 16, 0, 0);
}

// ---------------- converts ----------------
__global__ __launch_bounds__(256) void cvt_bf16_kernel(const float* __restrict__ in,
                                                       u16* __restrict__ out, int n) {
  int i = blockIdx.x * 256 + threadIdx.x;
  int stride = gridDim.x * 256;
  for (; i < n; i += stride) out[i] = f2bf(in[i]);
}

// W_xproj [96][2048] -> padded bf16 [128][2048] (rows 96..127 zero)
__global__ __launch_bounds__(256) void cvt_pad_xproj_kernel(const float* __restrict__ in,
                                                            u16* __restrict__ out) {
  int i = blockIdx.x * 256 + threadIdx.x;  // 128*2048
  int r = i >> 11, c = i & (DI - 1);
  out[i] = (r < 96) ? f2bf(in[r * DI + c]) : (u16)0;
}

// ---------------- RMSNorm -> bf16 ----------------
__global__ __launch_bounds__(256) void rmsnorm_kernel(const float* __restrict__ x,
                                                      const float* __restrict__ w,
                                                      u16* __restrict__ xn) {
  const int row = blockIdx.x;
  const int tid = threadIdx.x;
  const float4 v = reinterpret_cast<const float4*>(x + (size_t)row * DM)[tid];
  float ss = v.x * v.x + v.y * v.y + v.z * v.z + v.w * v.w;
#pragma unroll
  for (int o = 32; o; o >>= 1) ss += __shfl_xor(ss, o);
  __shared__ float red[4];
  if ((tid & 63) == 0) red[tid >> 6] = ss;
  __syncthreads();
  const float tot = red[0] + red[1] + red[2] + red[3];
  const float scale = rsqrtf(tot * (1.0f / DM) + 1e-5f);
  const float4 wv = reinterpret_cast<const float4*>(w)[tid];
  ushort4 o4;
  o4.x = f2bf(v.x * scale * wv.x);
  o4.y = f2bf(v.y * scale * wv.y);
  o4.z = f2bf(v.z * scale * wv.z);
  o4.w = f2bf(v.w * scale * wv.w);
  *reinterpret_cast<ushort4*>(&xn[(size_t)row * DM + tid * 4]) = o4;
}

// ---------------- MFMA GEMM: C[M,N] = A[M,K] * B[N,K]^T, bf16 in / f32 acc ----------------
// EPI 0: store bf16 -> outB[row*N+col]                     (in_proj -> xz)
// EPI 1: store f32 -> outF[row*96+col] (col<96), bf16 -> out2B[row*64+col] (col<64)  (x_proj)
// EPI 2: store f32 softplus(acc + aux[col]) -> outF        (dt proj)
// EPI 3: store f32 acc + resid[row*N+col] -> outF          (out_proj + residual)
template <int EPI>
__global__ __launch_bounds__(256) void gemm_bt(const u16* __restrict__ A,
                                               const u16* __restrict__ Bw,
                                               int M, int N, int K,
                                               float* __restrict__ outF,
                                               u16* __restrict__ outB,
                                               const float* __restrict__ aux,
                                               const float* __restrict__ resid,
                                               u16* __restrict__ out2B) {
  __shared__ __align__(16) u16 As[128 * 32];
  __shared__ __align__(16) u16 Bs[128 * 32];
  const int tid = threadIdx.x;
  const int lane = tid & 63;
  const int wid = tid >> 6;
  const int wr = wid >> 1, wc = wid & 1;
  const int bm = blockIdx.y * 128, bn = blockIdx.x * 128;
  const int r0 = tid >> 2;          // staging row (0..63)
  const int c0 = (tid & 3) * 8;     // staging col (elements)
  const int lrow = lane & 15, kq = lane >> 4;

  f32x4 acc[4][4] = {};

  const u16* Ab = A + (size_t)bm * K;
  const u16* Bb = Bw + (size_t)bn * K;

  for (int k0 = 0; k0 < K; k0 += 32) {
    gload16(Ab + (size_t)r0 * K + k0 + c0, &As[r0 * 32 + c0]);
    gload16(Ab + (size_t)(r0 + 64) * K + k0 + c0, &As[(r0 + 64) * 32 + c0]);
    gload16(Bb + (size_t)r0 * K + k0 + c0, &Bs[r0 * 32 + c0]);
    gload16(Bb + (size_t)(r0 + 64) * K + k0 + c0, &Bs[(r0 + 64) * 32 + c0]);
    __syncthreads();
    bf16x8 af[4], bfr[4];
#pragma unroll
    for (int m = 0; m < 4; ++m)
      af[m] = *reinterpret_cast<const bf16x8*>(&As[(wr * 64 + m * 16 + lrow) * 32 + kq * 8]);
#pragma unroll
    for (int n = 0; n < 4; ++n)
      bfr[n] = *reinterpret_cast<const bf16x8*>(&Bs[(wc * 64 + n * 16 + lrow) * 32 + kq * 8]);
#pragma unroll
    for (int m = 0; m < 4; ++m)
#pragma unroll
      for (int n = 0; n < 4; ++n)
        acc[m][n] = __builtin_amdgcn_mfma_f32_16x16x32_bf16(af[m], bfr[n], acc[m][n], 0, 0, 0);
    __syncthreads();
  }

#pragma unroll
  for (int m = 0; m < 4; ++m) {
#pragma unroll
    for (int n = 0; n < 4; ++n) {
      const int col = bn + wc * 64 + n * 16 + lrow;
#pragma unroll
      for (int r = 0; r < 4; ++r) {
        const int row = bm + wr * 64 + m * 16 + kq * 4 + r;
        const float v = acc[m][n][r];
        if (EPI == 0) {
          outB[(size_t)row * N + col] = f2bf(v);
        } else if (EPI == 1) {
          if (col < 96) outF[(size_t)row * 96 + col] = v;
          if (col < 64) out2B[(size_t)row * 64 + col] = f2bf(v);
        } else if (EPI == 2) {
          const float xv = v + aux[col];
          const float sp = fmaxf(xv, 0.f) + log1pf(__expf(-fabsf(xv)));
          outF[(size_t)row * N + col] = sp;
        } else {
          outF[(size_t)row * N + col] = v + resid[(size_t)row * N + col];
        }
      }
    }
  }
}

// ---------------- depthwise causal conv1d + silu ----------------
__global__ __launch_bounds__(256) void conv_silu_kernel(const u16* __restrict__ xz,
                                                        const float* __restrict__ Wc,
                                                        const float* __restrict__ bc,
                                                        u16* __restrict__ uc) {
  const int id = blockIdx.x * 256 + threadIdx.x;  // 2*2048*2048 = 2^23
  const int d = id & (DI - 1);
  const int t = (id >> 11) & (LS - 1);
  const int b = id >> 22;
  const size_t rowb = (size_t)b * LS;
  const float4 w = *reinterpret_cast<const float4*>(&Wc[d * 4]);
  const float wv[4] = {w.x, w.y, w.z, w.w};
  float s = bc[d];
#pragma unroll
  for (int k = 0; k < 4; ++k) {
    const int tt = t - 3 + k;
    if (tt >= 0) s += bf2f(xz[(rowb + tt) * (2 * DI) + d]) * wv[k];
  }
  const float sl = s / (1.f + __expf(-s));
  uc[(rowb + t) * DI + d] = f2bf(sl);
}

// ---------------- selective scan (+ gating epilogue -> bf16 y) ----------------
// 4 threads per (b,d); each owns 4 states. 16384 threads total.
__global__ __launch_bounds__(256) void scan_kernel(const float* __restrict__ dtf,
                                                   const float* __restrict__ xdbl,
                                                   const u16* __restrict__ uc,
                                                   const u16* __restrict__ xz,
                                                   const float* __restrict__ Alog,
                                                   const float* __restrict__ Dp,
                                                   u16* __restrict__ yb) {
  const int gid = blockIdx.x * 256 + threadIdx.x;
  const int ng = gid & 3;
  const int ch = gid >> 2;  // 0..4095
  const int d = ch & (DI - 1);
  const int b = ch >> 11;
  float Ar[4];
#pragma unroll
  for (int j = 0; j < 4; ++j) Ar[j] = -__expf(Alog[d * DSn + ng * 4 + j]);
  const float Dd = Dp[d];
  float h0 = 0.f, h1 = 0.f, h2 = 0.f, h3 = 0.f;
  const size_t base = (size_t)b * LS;
  const float* dtp = dtf + base * DI + d;
  const u16* ucp = uc + base * DI + d;
  const u16* zp = xz + base * (2 * DI) + DI + d;
  const float* xd = xdbl + base * 96;
  u16* yp = yb + base * DI + d;
  for (int t = 0; t < LS; ++t) {
    const float dtv = dtp[(size_t)t * DI];
    const float uv = bf2f(ucp[(size_t)t * DI]);
    const float4 Bv = *reinterpret_cast<const float4*>(&xd[t * 96 + DTRk + ng * 4]);
    const float4 Cv = *reinterpret_cast<const float4*>(&xd[t * 96 + DTRk + DSn + ng * 4]);
    const float du = dtv * uv;
    h0 = __expf(dtv * Ar[0]) * h0 + du * Bv.x;
    h1 = __expf(dtv * Ar[1]) * h1 + du * Bv.y;
    h2 = __expf(dtv * Ar[2]) * h2 + du * Bv.z;
    h3 = __expf(dtv * Ar[3]) * h3 + du * Bv.w;
    float y = h0 * Cv.x + h1 * Cv.y + h2 * Cv.z + h3 * Cv.w;
    y += __shfl_xor(y, 1);
    y += __shfl_xor(y, 2);
    if (ng == 0) {
      const float z = bf2f(zp[(size_t)t * (2 * DI)]);
      const float sz = z / (1.f + __expf(-z));
      const float yg = (y + uv * Dd) * sz;
      yp[(size_t)t * DI] = f2bf(yg);
    }
  }
}

extern "C" void kernel_launch(void* const* d_in, const int* in_sizes, int n_in,
                              void* d_out, int out_size, void* d_ws, size_t ws_size,
                              hipStream_t stream) {
  (void)in_sizes; (void)n_in; (void)out_size; (void)ws_size;
  const float* x      = (const float*)d_in[0];
  const float* norm_w = (const float*)d_in[1];
  const float* W_in   = (const float*)d_in[2];
  const float* W_conv = (const float*)d_in[3];
  const float* b_conv = (const float*)d_in[4];
  const float* W_xp   = (const float*)d_in[5];
  const float* W_dt   = (const float*)d_in[6];
  const float* b_dt   = (const float*)d_in[7];
  const float* A_log  = (const float*)d_in[8];
  const float* Dvec   = (const float*)d_in[9];
  const float* W_out  = (const float*)d_in[10];
  float* out = (float*)d_out;

  char* ws = (char*)d_ws;
  size_t off = 0;
  auto alloc = [&](size_t bytes) -> void* {
    void* p = ws + off;
    off += (bytes + 255) & ~(size_t)255;
    return p;
  };
  u16* Win_b  = (u16*)alloc((size_t)4096 * 1024 * 2);
  u16* Wout_b = (u16*)alloc((size_t)1024 * 2048 * 2);
  u16* Wxp_b  = (u16*)alloc((size_t)128 * 2048 * 2);
  u16* Wdt_b  = (u16*)alloc((size_t)2048 * 64 * 2);
  u16* xn_b   = (u16*)alloc((size_t)MR * DM * 2);
  u16* xz_b   = (u16*)alloc((size_t)MR * 2 * DI * 2);
  u16* uc_b   = (u16*)alloc((size_t)MR * DI * 2);
  float* xdbl = (float*)alloc((size_t)MR * 96 * 4);
  u16* dtr_b  = (u16*)alloc((size_t)MR * 64 * 2);
  float* dtf  = (float*)alloc((size_t)MR * DI * 4);
  u16* y_b    = (u16*)alloc((size_t)MR * DI * 2);

  cvt_bf16_kernel<<<2048, 256, 0, stream>>>(W_in, Win_b, 4096 * 1024);
  cvt_bf16_kernel<<<2048, 256, 0, stream>>>(W_out, Wout_b, 1024 * 2048);
  cvt_bf16_kernel<<<512, 256, 0, stream>>>(W_dt, Wdt_b, 2048 * 64);
  cvt_pad_xproj_kernel<<<1024, 256, 0, stream>>>(W_xp, Wxp_b);

  rmsnorm_kernel<<<MR, 256, 0, stream>>>(x, norm_w, xn_b);

  // xz = xn @ W_in^T : [4096,4096]
  gemm_bt<0><<<dim3(32, 32), 256, 0, stream>>>(xn_b, Win_b, MR, 4096, 1024,
                                               nullptr, xz_b, nullptr, nullptr, nullptr);
  // depthwise conv + silu -> u_conv
  conv_silu_kernel<<<32768, 256, 0, stream>>>(xz_b, W_conv, b_conv, uc_b);
  // x_dbl = u_conv @ W_xproj^T : [4096,96] (padded N=128)
  gemm_bt<1><<<dim3(1, 32), 256, 0, stream>>>(uc_b, Wxp_b, MR, 128, 2048,
                                              xdbl, nullptr, nullptr, nullptr, dtr_b);
  // dt = softplus(dtr @ W_dt^T + b_dt) : [4096,2048]
  gemm_bt<2><<<dim3(16, 32), 256, 0, stream>>>(dtr_b, Wdt_b, MR, 2048, 64,
                                               dtf, nullptr, b_dt, nullptr, nullptr);
  // selective scan + gating -> y_b (bf16)
  scan_kernel<<<64, 256, 0, stream>>>(dtf, xdbl, uc_b, xz_b, A_log, Dvec, y_b);
  // out = y @ W_out^T + x
  gemm_bt<3><<<dim3(8, 32), 256, 0, stream>>>(y_b, Wout_b, MR, 1024, 2048,
                                              out, nullptr, nullptr, x, nullptr);
}

// Round 2
// 324.905 us; speedup vs baseline: 5.2222x; 5.2222x over previous
//
#include <hip/hip_runtime.h>

typedef unsigned short u16;
typedef unsigned int u32;
typedef short bf16x8 __attribute__((ext_vector_type(8)));
typedef float f32x4 __attribute__((ext_vector_type(4)));

static constexpr int LS = 2048;   // seq len
static constexpr int DM = 1024;   // d_model
static constexpr int DI = 2048;   // d_inner
static constexpr int DSn = 16;    // d_state
static constexpr int DTRk = 64;   // dt_rank
static constexpr int MR = 4096;   // B*L rows
static constexpr int NCH = 32;    // scan chunks
static constexpr int CL = LS / NCH;  // 64 timesteps per chunk

#define DEV __device__ __forceinline__

DEV u16 f2bf(float f) {
  u32 u = __float_as_uint(f);
  u32 r = (u + 0x7FFF + ((u >> 16) & 1)) >> 16;
  return (u16)r;
}
DEV float bf2f(u16 h) { return __uint_as_float(((u32)h) << 16); }

DEV void gload16(const u16* g, u16* l) {
  __builtin_amdgcn_global_load_lds((const __attribute__((address_space(1))) u32*)g,
                                   (__attribute__((address_space(3))) u32*)l, 16, 0, 0);
}

// ---------------- converts ----------------
__global__ __launch_bounds__(256) void cvt_bf16_kernel(const float* __restrict__ in,
                                                       u16* __restrict__ out, int n) {
  int i = blockIdx.x * 256 + threadIdx.x;
  int stride = gridDim.x * 256;
  for (; i < n; i += stride) out[i] = f2bf(in[i]);
}

// W_xproj [96][2048] -> padded bf16 [128][2048] (rows 96..127 zero)
__global__ __launch_bounds__(256) void cvt_pad_xproj_kernel(const float* __restrict__ in,
                                                            u16* __restrict__ out) {
  int i = blockIdx.x * 256 + threadIdx.x;  // 128*2048
  int r = i >> 11, c = i & (DI - 1);
  out[i] = (r < 96) ? f2bf(in[r * DI + c]) : (u16)0;
}

// ---------------- RMSNorm -> bf16 ----------------
__global__ __launch_bounds__(256) void rmsnorm_kernel(const float* __restrict__ x,
                                                      const float* __restrict__ w,
                                                      u16* __restrict__ xn) {
  const int row = blockIdx.x;
  const int tid = threadIdx.x;
  const float4 v = reinterpret_cast<const float4*>(x + (size_t)row * DM)[tid];
  float ss = v.x * v.x + v.y * v.y + v.z * v.z + v.w * v.w;
#pragma unroll
  for (int o = 32; o; o >>= 1) ss += __shfl_xor(ss, o);
  __shared__ float red[4];
  if ((tid & 63) == 0) red[tid >> 6] = ss;
  __syncthreads();
  const float tot = red[0] + red[1] + red[2] + red[3];
  const float scale = rsqrtf(tot * (1.0f / DM) + 1e-5f);
  const float4 wv = reinterpret_cast<const float4*>(w)[tid];
  ushort4 o4;
  o4.x = f2bf(v.x * scale * wv.x);
  o4.y = f2bf(v.y * scale * wv.y);
  o4.z = f2bf(v.z * scale * wv.z);
  o4.w = f2bf(v.w * scale * wv.w);
  *reinterpret_cast<ushort4*>(&xn[(size_t)row * DM + tid * 4]) = o4;
}

// ---------------- MFMA GEMM: C[M,N] = A[M,K] * B[N,K]^T, bf16 in / f32 acc ----------------
template <int EPI>
__global__ __launch_bounds__(256) void gemm_bt(const u16* __restrict__ A,
                                               const u16* __restrict__ Bw,
                                               int M, int N, int K,
                                               float* __restrict__ outF,
                                               u16* __restrict__ outB,
                                               const float* __restrict__ aux,
                                               const float* __restrict__ resid,
                                               u16* __restrict__ out2B) {
  __shared__ __align__(16) u16 As[128 * 32];
  __shared__ __align__(16) u16 Bs[128 * 32];
  const int tid = threadIdx.x;
  const int lane = tid & 63;
  const int wid = tid >> 6;
  const int wr = wid >> 1, wc = wid & 1;
  const int bm = blockIdx.y * 128, bn = blockIdx.x * 128;
  const int r0 = tid >> 2;          // staging row (0..63)
  const int c0 = (tid & 3) * 8;     // staging col (elements)
  const int lrow = lane & 15, kq = lane >> 4;

  f32x4 acc[4][4] = {};

  const u16* Ab = A + (size_t)bm * K;
  const u16* Bb = Bw + (size_t)bn * K;

  for (int k0 = 0; k0 < K; k0 += 32) {
    gload16(Ab + (size_t)r0 * K + k0 + c0, &As[r0 * 32 + c0]);
    gload16(Ab + (size_t)(r0 + 64) * K + k0 + c0, &As[(r0 + 64) * 32 + c0]);
    gload16(Bb + (size_t)r0 * K + k0 + c0, &Bs[r0 * 32 + c0]);
    gload16(Bb + (size_t)(r0 + 64) * K + k0 + c0, &Bs[(r0 + 64) * 32 + c0]);
    __syncthreads();
    bf16x8 af[4], bfr[4];
#pragma unroll
    for (int m = 0; m < 4; ++m)
      af[m] = *reinterpret_cast<const bf16x8*>(&As[(wr * 64 + m * 16 + lrow) * 32 + kq * 8]);
#pragma unroll
    for (int n = 0; n < 4; ++n)
      bfr[n] = *reinterpret_cast<const bf16x8*>(&Bs[(wc * 64 + n * 16 + lrow) * 32 + kq * 8]);
#pragma unroll
    for (int m = 0; m < 4; ++m)
#pragma unroll
      for (int n = 0; n < 4; ++n)
        acc[m][n] = __builtin_amdgcn_mfma_f32_16x16x32_bf16(af[m], bfr[n], acc[m][n], 0, 0, 0);
    __syncthreads();
  }

#pragma unroll
  for (int m = 0; m < 4; ++m) {
#pragma unroll
    for (int n = 0; n < 4; ++n) {
      const int col = bn + wc * 64 + n * 16 + lrow;
#pragma unroll
      for (int r = 0; r < 4; ++r) {
        const int row = bm + wr * 64 + m * 16 + kq * 4 + r;
        const float v = acc[m][n][r];
        if (EPI == 0) {
          outB[(size_t)row * N + col] = f2bf(v);
        } else if (EPI == 1) {
          if (col < 96) outF[(size_t)row * 96 + col] = v;
          if (col < 64) out2B[(size_t)row * 64 + col] = f2bf(v);
        } else if (EPI == 2) {
          const float xv = v + aux[col];
          const float sp = fmaxf(xv, 0.f) + log1pf(__expf(-fabsf(xv)));
          outF[(size_t)row * N + col] = sp;
        } else {
          outF[(size_t)row * N + col] = v + resid[(size_t)row * N + col];
        }
      }
    }
  }
}

// ---------------- depthwise causal conv1d + silu ----------------
__global__ __launch_bounds__(256) void conv_silu_kernel(const u16* __restrict__ xz,
                                                        const float* __restrict__ Wc,
                                                        const float* __restrict__ bc,
                                                        u16* __restrict__ uc) {
  const int id = blockIdx.x * 256 + threadIdx.x;  // 2*2048*2048 = 2^23
  const int d = id & (DI - 1);
  const int t = (id >> 11) & (LS - 1);
  const int b = id >> 22;
  const size_t rowb = (size_t)b * LS;
  const float4 w = *reinterpret_cast<const float4*>(&Wc[d * 4]);
  const float wv[4] = {w.x, w.y, w.z, w.w};
  float s = bc[d];
#pragma unroll
  for (int k = 0; k < 4; ++k) {
    const int tt = t - 3 + k;
    if (tt >= 0) s += bf2f(xz[(rowb + tt) * (2 * DI) + d]) * wv[k];
  }
  const float sl = s / (1.f + __expf(-s));
  uc[(rowb + t) * DI + d] = f2bf(sl);
}

// ---------------- chunked selective scan ----------------
// Thread mapping (phase 1 & 3): gid -> ng = gid&3 (4 states each),
// d = (gid>>2)&2047, c = (gid>>13)&31 ... actually c bits after d:
//   ch2 = gid>>2; d = ch2 & (DI-1); c = (ch2>>11) & (NCH-1); b = ch2>>16.
// Grid: B*NCH*DI*4 / 256 = 2048 blocks.

// Phase 1: local scan from h=0 over the chunk; emit S (final local state)
// and P = exp(A * sum_dt) (exact chunk decay product).
__global__ __launch_bounds__(256) void scan_phase1(const float* __restrict__ dtf,
                                                   const float* __restrict__ xdbl,
                                                   const u16* __restrict__ uc,
                                                   const float* __restrict__ Alog,
                                                   float* __restrict__ P,
                                                   float* __restrict__ S) {
  const int gid = blockIdx.x * 256 + threadIdx.x;
  const int ng = gid & 3;
  const int ch2 = gid >> 2;
  const int d = ch2 & (DI - 1);
  const int c = (ch2 >> 11) & (NCH - 1);
  const int b = ch2 >> 16;
  float Ar[4];
#pragma unroll
  for (int j = 0; j < 4; ++j) Ar[j] = -__expf(Alog[d * DSn + ng * 4 + j]);
  float h0 = 0.f, h1 = 0.f, h2 = 0.f, h3 = 0.f, sdt = 0.f;
  const size_t tbase = (size_t)b * LS + c * CL;
  const float* dtp = dtf + tbase * DI + d;
  const u16* ucp = uc + tbase * DI + d;
  const float* xd = xdbl + tbase * 96 + DTRk + ng * 4;
  for (int t = 0; t < CL; ++t) {
    const float dtv = dtp[(size_t)t * DI];
    const float uv = bf2f(ucp[(size_t)t * DI]);
    const float4 Bv = *reinterpret_cast<const float4*>(&xd[t * 96]);
    const float du = dtv * uv;
    sdt += dtv;
    h0 = __expf(dtv * Ar[0]) * h0 + du * Bv.x;
    h1 = __expf(dtv * Ar[1]) * h1 + du * Bv.y;
    h2 = __expf(dtv * Ar[2]) * h2 + du * Bv.z;
    h3 = __expf(dtv * Ar[3]) * h3 + du * Bv.w;
  }
  const size_t oi = (((size_t)b * NCH + c) * DI + d) * DSn + ng * 4;
  float4 Sv = {h0, h1, h2, h3};
  float4 Pv = {__expf(Ar[0] * sdt), __expf(Ar[1] * sdt), __expf(Ar[2] * sdt), __expf(Ar[3] * sdt)};
  *reinterpret_cast<float4*>(&S[oi]) = Sv;
  *reinterpret_cast<float4*>(&P[oi]) = Pv;
}

// Phase 3: compose incoming state from preceding chunks' (P,S), then re-scan
// the chunk computing y, add D*u, gate with silu(z), store bf16 y.
__global__ __launch_bounds__(256) void scan_phase3(const float* __restrict__ dtf,
                                                   const float* __restrict__ xdbl,
                                                   const u16* __restrict__ uc,
                                                   const u16* __restrict__ xz,
                                                   const float* __restrict__ Alog,
                                                   const float* __restrict__ Dp,
                                                   const float* __restrict__ P,
                                                   const float* __restrict__ S,
                                                   u16* __restrict__ yb) {
  const int gid = blockIdx.x * 256 + threadIdx.x;
  const int ng = gid & 3;
  const int ch2 = gid >> 2;
  const int d = ch2 & (DI - 1);
  const int c = (ch2 >> 11) & (NCH - 1);
  const int b = ch2 >> 16;
  float Ar[4];
#pragma unroll
  for (int j = 0; j < 4; ++j) Ar[j] = -__expf(Alog[d * DSn + ng * 4 + j]);
  const float Dd = Dp[d];
  // compose h_in from chunks 0..c-1
  float h0 = 0.f, h1 = 0.f, h2 = 0.f, h3 = 0.f;
  for (int cc = 0; cc < c; ++cc) {
    const size_t oi = (((size_t)b * NCH + cc) * DI + d) * DSn + ng * 4;
    const float4 Pv = *reinterpret_cast<const float4*>(&P[oi]);
    const float4 Sv = *reinterpret_cast<const float4*>(&S[oi]);
    h0 = Sv.x + Pv.x * h0;
    h1 = Sv.y + Pv.y * h1;
    h2 = Sv.z + Pv.z * h2;
    h3 = Sv.w + Pv.w * h3;
  }
  const size_t tbase = (size_t)b * LS + c * CL;
  const float* dtp = dtf + tbase * DI + d;
  const u16* ucp = uc + tbase * DI + d;
  const u16* zp = xz + tbase * (2 * DI) + DI + d;
  const float* xd = xdbl + tbase * 96 + DTRk + ng * 4;
  u16* yp = yb + tbase * DI + d;
  for (int t = 0; t < CL; ++t) {
    const float dtv = dtp[(size_t)t * DI];
    const float uv = bf2f(ucp[(size_t)t * DI]);
    const float4 Bv = *reinterpret_cast<const float4*>(&xd[t * 96]);
    const float4 Cv = *reinterpret_cast<const float4*>(&xd[t * 96 + DSn]);
    const float du = dtv * uv;
    h0 = __expf(dtv * Ar[0]) * h0 + du * Bv.x;
    h1 = __expf(dtv * Ar[1]) * h1 + du * Bv.y;
    h2 = __expf(dtv * Ar[2]) * h2 + du * Bv.z;
    h3 = __expf(dtv * Ar[3]) * h3 + du * Bv.w;
    float y = h0 * Cv.x + h1 * Cv.y + h2 * Cv.z + h3 * Cv.w;
    y += __shfl_xor(y, 1);
    y += __shfl_xor(y, 2);
    if (ng == 0) {
      const float z = bf2f(zp[(size_t)t * (2 * DI)]);
      const float sz = z / (1.f + __expf(-z));
      const float yg = (y + uv * Dd) * sz;
      yp[(size_t)t * DI] = f2bf(yg);
    }
  }
}

extern "C" void kernel_launch(void* const* d_in, const int* in_sizes, int n_in,
                              void* d_out, int out_size, void* d_ws, size_t ws_size,
                              hipStream_t stream) {
  (void)in_sizes; (void)n_in; (void)out_size; (void)ws_size;
  const float* x      = (const float*)d_in[0];
  const float* norm_w = (const float*)d_in[1];
  const float* W_in   = (const float*)d_in[2];
  const float* W_conv = (const float*)d_in[3];
  const float* b_conv = (const float*)d_in[4];
  const float* W_xp   = (const float*)d_in[5];
  const float* W_dt   = (const float*)d_in[6];
  const float* b_dt   = (const float*)d_in[7];
  const float* A_log  = (const float*)d_in[8];
  const float* Dvec   = (const float*)d_in[9];
  const float* W_out  = (const float*)d_in[10];
  float* out = (float*)d_out;

  char* ws = (char*)d_ws;
  size_t off = 0;
  auto alloc = [&](size_t bytes) -> void* {
    void* p = ws + off;
    off += (bytes + 255) & ~(size_t)255;
    return p;
  };
  u16* Win_b  = (u16*)alloc((size_t)4096 * 1024 * 2);   // 8 MB (dead after gemm<0>)
  u16* Wout_b = (u16*)alloc((size_t)1024 * 2048 * 2);
  u16* Wxp_b  = (u16*)alloc((size_t)128 * 2048 * 2);
  u16* Wdt_b  = (u16*)alloc((size_t)2048 * 64 * 2);
  u16* xn_b   = (u16*)alloc((size_t)MR * DM * 2);       // 8 MB (dead after gemm<0>)
  u16* xz_b   = (u16*)alloc((size_t)MR * 2 * DI * 2);
  u16* uc_b   = (u16*)alloc((size_t)MR * DI * 2);
  float* xdbl = (float*)alloc((size_t)MR * 96 * 4);
  u16* dtr_b  = (u16*)alloc((size_t)MR * 64 * 2);
  float* dtf  = (float*)alloc((size_t)MR * DI * 4);
  u16* y_b    = (u16*)alloc((size_t)MR * DI * 2);
  // scan chunk buffers alias regions dead by the time phase1 runs:
  // P,S each B*NCH*DI*16*4 = 8 MB exactly.
  float* Pbuf = (float*)Win_b;
  float* Sbuf = (float*)xn_b;

  cvt_bf16_kernel<<<2048, 256, 0, stream>>>(W_in, Win_b, 4096 * 1024);
  cvt_bf16_kernel<<<2048, 256, 0, stream>>>(W_out, Wout_b, 1024 * 2048);
  cvt_bf16_kernel<<<512, 256, 0, stream>>>(W_dt, Wdt_b, 2048 * 64);
  cvt_pad_xproj_kernel<<<1024, 256, 0, stream>>>(W_xp, Wxp_b);

  rmsnorm_kernel<<<MR, 256, 0, stream>>>(x, norm_w, xn_b);

  // xz = xn @ W_in^T : [4096,4096]
  gemm_bt<0><<<dim3(32, 32), 256, 0, stream>>>(xn_b, Win_b, MR, 4096, 1024,
                                               nullptr, xz_b, nullptr, nullptr, nullptr);
  // depthwise conv + silu -> u_conv
  conv_silu_kernel<<<32768, 256, 0, stream>>>(xz_b, W_conv, b_conv, uc_b);
  // x_dbl = u_conv @ W_xproj^T : [4096,96] (padded N=128)
  gemm_bt<1><<<dim3(1, 32), 256, 0, stream>>>(uc_b, Wxp_b, MR, 128, 2048,
                                              xdbl, nullptr, nullptr, nullptr, dtr_b);
  // dt = softplus(dtr @ W_dt^T + b_dt) : [4096,2048]
  gemm_bt<2><<<dim3(16, 32), 256, 0, stream>>>(dtr_b, Wdt_b, MR, 2048, 64,
                                               dtf, nullptr, b_dt, nullptr, nullptr);
  // chunked selective scan (phase1: local scans; phase3: compose + rescan + gate)
  scan_phase1<<<2048, 256, 0, stream>>>(dtf, xdbl, uc_b, A_log, Pbuf, Sbuf);
  scan_phase3<<<2048, 256, 0, stream>>>(dtf, xdbl, uc_b, xz_b, A_log, Dvec,
                                        Pbuf, Sbuf, y_b);
  // out = y @ W_out^T + x
  gemm_bt<3><<<dim3(8, 32), 256, 0, stream>>>(y_b, Wout_b, MR, 1024, 2048,
                                              out, nullptr, nullptr, x, nullptr);
}

// Round 3
// 291.780 us; speedup vs baseline: 5.8150x; 1.1135x over previous
//
#include <hip/hip_runtime.h>

typedef unsigned short u16;
typedef unsigned int u32;
typedef short bf16x8 __attribute__((ext_vector_type(8)));
typedef float f32x4 __attribute__((ext_vector_type(4)));

static constexpr int LS = 2048;   // seq len
static constexpr int DM = 1024;   // d_model
static constexpr int DI = 2048;   // d_inner
static constexpr int DSn = 16;    // d_state
static constexpr int DTRk = 64;   // dt_rank
static constexpr int MR = 4096;   // B*L rows
static constexpr int NCH = 32;    // scan chunks
static constexpr int CL = LS / NCH;  // 64 timesteps per chunk

#define DEV __device__ __forceinline__

DEV u16 f2bf(float f) {
  u32 u = __float_as_uint(f);
  u32 r = (u + 0x7FFF + ((u >> 16) & 1)) >> 16;
  return (u16)r;
}
DEV float bf2f(u16 h) { return __uint_as_float(((u32)h) << 16); }

DEV void gload16(const u16* g, u16* l) {
  __builtin_amdgcn_global_load_lds((const __attribute__((address_space(1))) u32*)g,
                                   (__attribute__((address_space(3))) u32*)l, 16, 0, 0);
}

// ---------------- converts ----------------
__global__ __launch_bounds__(256) void cvt_bf16_kernel(const float* __restrict__ in,
                                                       u16* __restrict__ out, int n) {
  int i = blockIdx.x * 256 + threadIdx.x;
  int stride = gridDim.x * 256;
  for (; i < n; i += stride) out[i] = f2bf(in[i]);
}

// W_xproj [96][2048] -> padded bf16 [128][2048] (rows 96..127 zero)
__global__ __launch_bounds__(256) void cvt_pad_xproj_kernel(const float* __restrict__ in,
                                                            u16* __restrict__ out) {
  int i = blockIdx.x * 256 + threadIdx.x;  // 128*2048
  int r = i >> 11, c = i & (DI - 1);
  out[i] = (r < 96) ? f2bf(in[r * DI + c]) : (u16)0;
}

// ---------------- RMSNorm -> bf16 ----------------
__global__ __launch_bounds__(256) void rmsnorm_kernel(const float* __restrict__ x,
                                                      const float* __restrict__ w,
                                                      u16* __restrict__ xn) {
  const int row = blockIdx.x;
  const int tid = threadIdx.x;
  const float4 v = reinterpret_cast<const float4*>(x + (size_t)row * DM)[tid];
  float ss = v.x * v.x + v.y * v.y + v.z * v.z + v.w * v.w;
#pragma unroll
  for (int o = 32; o; o >>= 1) ss += __shfl_xor(ss, o);
  __shared__ float red[4];
  if ((tid & 63) == 0) red[tid >> 6] = ss;
  __syncthreads();
  const float tot = red[0] + red[1] + red[2] + red[3];
  const float scale = rsqrtf(tot * (1.0f / DM) + 1e-5f);
  const float4 wv = reinterpret_cast<const float4*>(w)[tid];
  ushort4 o4;
  o4.x = f2bf(v.x * scale * wv.x);
  o4.y = f2bf(v.y * scale * wv.y);
  o4.z = f2bf(v.z * scale * wv.z);
  o4.w = f2bf(v.w * scale * wv.w);
  *reinterpret_cast<ushort4*>(&xn[(size_t)row * DM + tid * 4]) = o4;
}

// ---------------- MFMA GEMM: C[M,N] = A[M,K] * B[N,K]^T, bf16 in / f32 acc ----------------
// EPI 0: store bf16 -> outB           (in_proj -> xz)
// EPI 2: store f32 softplus(acc+aux[col]) -> outF   (dt proj)
// EPI 3: store f32 acc + resid -> outF              (out_proj + residual)
template <int EPI>
__global__ __launch_bounds__(256) void gemm_bt(const u16* __restrict__ A,
                                               const u16* __restrict__ Bw,
                                               int M, int N, int K,
                                               float* __restrict__ outF,
                                               u16* __restrict__ outB,
                                               const float* __restrict__ aux,
                                               const float* __restrict__ resid) {
  __shared__ __align__(16) u16 As[128 * 32];
  __shared__ __align__(16) u16 Bs[128 * 32];
  const int tid = threadIdx.x;
  const int lane = tid & 63;
  const int wid = tid >> 6;
  const int wr = wid >> 1, wc = wid & 1;
  // XCD-aware bijective swizzle (all grids here have nwg % 8 == 0)
  const int nwg = gridDim.x * gridDim.y;
  int wg = blockIdx.y * gridDim.x + blockIdx.x;
  wg = (wg & 7) * (nwg >> 3) + (wg >> 3);
  const int bn = (wg % gridDim.x) * 128;
  const int bm = (wg / gridDim.x) * 128;
  const int r0 = tid >> 2;          // staging row (0..63)
  const int c0 = (tid & 3) * 8;     // staging col (elements)
  const int lrow = lane & 15, kq = lane >> 4;

  f32x4 acc[4][4] = {};

  const u16* Ab = A + (size_t)bm * K;
  const u16* Bb = Bw + (size_t)bn * K;

  for (int k0 = 0; k0 < K; k0 += 32) {
    gload16(Ab + (size_t)r0 * K + k0 + c0, &As[r0 * 32 + c0]);
    gload16(Ab + (size_t)(r0 + 64) * K + k0 + c0, &As[(r0 + 64) * 32 + c0]);
    gload16(Bb + (size_t)r0 * K + k0 + c0, &Bs[r0 * 32 + c0]);
    gload16(Bb + (size_t)(r0 + 64) * K + k0 + c0, &Bs[(r0 + 64) * 32 + c0]);
    __syncthreads();
    bf16x8 af[4], bfr[4];
#pragma unroll
    for (int m = 0; m < 4; ++m)
      af[m] = *reinterpret_cast<const bf16x8*>(&As[(wr * 64 + m * 16 + lrow) * 32 + kq * 8]);
#pragma unroll
    for (int n = 0; n < 4; ++n)
      bfr[n] = *reinterpret_cast<const bf16x8*>(&Bs[(wc * 64 + n * 16 + lrow) * 32 + kq * 8]);
#pragma unroll
    for (int m = 0; m < 4; ++m)
#pragma unroll
      for (int n = 0; n < 4; ++n)
        acc[m][n] = __builtin_amdgcn_mfma_f32_16x16x32_bf16(af[m], bfr[n], acc[m][n], 0, 0, 0);
    __syncthreads();
  }

#pragma unroll
  for (int m = 0; m < 4; ++m) {
#pragma unroll
    for (int n = 0; n < 4; ++n) {
      const int col = bn + wc * 64 + n * 16 + lrow;
#pragma unroll
      for (int r = 0; r < 4; ++r) {
        const int row = bm + wr * 64 + m * 16 + kq * 4 + r;
        const float v = acc[m][n][r];
        if (EPI == 0) {
          outB[(size_t)row * N + col] = f2bf(v);
        } else if (EPI == 2) {
          const float xv = v + aux[col];
          const float sp = fmaxf(xv, 0.f) + log1pf(__expf(-fabsf(xv)));
          outF[(size_t)row * N + col] = sp;
        } else {
          outF[(size_t)row * N + col] = v + resid[(size_t)row * N + col];
        }
      }
    }
  }
}

// ---------------- x_proj GEMM, split-K over 8 parts of 256 ----------------
// grid (8, 32): blockIdx.x = kp, blockIdx.y = m-tile. N fixed 128, Kfull 2048.
__global__ __launch_bounds__(256) void gemm_xproj_splitk(const u16* __restrict__ A,
                                                         const u16* __restrict__ Bw,
                                                         float* __restrict__ p0,
                                                         float* __restrict__ p1) {
  __shared__ __align__(16) u16 As[128 * 32];
  __shared__ __align__(16) u16 Bs[128 * 32];
  const int tid = threadIdx.x;
  const int lane = tid & 63;
  const int wid = tid >> 6;
  const int wr = wid >> 1, wc = wid & 1;
  const int kp = blockIdx.x;
  const int bm = blockIdx.y * 128;
  const int koff = kp * 256;
  const int r0 = tid >> 2;
  const int c0 = (tid & 3) * 8;
  const int lrow = lane & 15, kq = lane >> 4;

  f32x4 acc[4][4] = {};
  const u16* Ab = A + (size_t)bm * DI + koff;
  const u16* Bb = Bw + koff;

  for (int k0 = 0; k0 < 256; k0 += 32) {
    gload16(Ab + (size_t)r0 * DI + k0 + c0, &As[r0 * 32 + c0]);
    gload16(Ab + (size_t)(r0 + 64) * DI + k0 + c0, &As[(r0 + 64) * 32 + c0]);
    gload16(Bb + (size_t)r0 * DI + k0 + c0, &Bs[r0 * 32 + c0]);
    gload16(Bb + (size_t)(r0 + 64) * DI + k0 + c0, &Bs[(r0 + 64) * 32 + c0]);
    __syncthreads();
    bf16x8 af[4], bfr[4];
#pragma unroll
    for (int m = 0; m < 4; ++m)
      af[m] = *reinterpret_cast<const bf16x8*>(&As[(wr * 64 + m * 16 + lrow) * 32 + kq * 8]);
#pragma unroll
    for (int n = 0; n < 4; ++n)
      bfr[n] = *reinterpret_cast<const bf16x8*>(&Bs[(wc * 64 + n * 16 + lrow) * 32 + kq * 8]);
#pragma unroll
    for (int m = 0; m < 4; ++m)
#pragma unroll
      for (int n = 0; n < 4; ++n)
        acc[m][n] = __builtin_amdgcn_mfma_f32_16x16x32_bf16(af[m], bfr[n], acc[m][n], 0, 0, 0);
    __syncthreads();
  }

  float* dst = (kp < 4 ? p0 : p1) + (size_t)(kp & 3) * MR * 128;
#pragma unroll
  for (int m = 0; m < 4; ++m)
#pragma unroll
    for (int n = 0; n < 4; ++n) {
      const int col = wc * 64 + n * 16 + lrow;
#pragma unroll
      for (int r = 0; r < 4; ++r) {
        const int row = bm + wr * 64 + m * 16 + kq * 4 + r;
        dst[(size_t)row * 128 + col] = acc[m][n][r];
      }
    }
}

// reduce 8 partial slices -> xdbl f32 (col<96) + dtr bf16 (col<64)
__global__ __launch_bounds__(256) void xproj_reduce(const float* __restrict__ p0,
                                                    const float* __restrict__ p1,
                                                    float* __restrict__ xdbl,
                                                    u16* __restrict__ dtr) {
  const int id = blockIdx.x * 256 + threadIdx.x;  // 4096*128
  const int row = id >> 7, col = id & 127;
  float s = 0.f;
#pragma unroll
  for (int kp = 0; kp < 4; ++kp) s += p0[(size_t)kp * MR * 128 + id];
#pragma unroll
  for (int kp = 0; kp < 4; ++kp) s += p1[(size_t)kp * MR * 128 + id];
  if (col < 96) xdbl[(size_t)row * 96 + col] = s;
  if (col < 64) dtr[(size_t)row * 64 + col] = f2bf(s);
}

// ---------------- depthwise causal conv1d + silu ----------------
__global__ __launch_bounds__(256) void conv_silu_kernel(const u16* __restrict__ xz,
                                                        const float* __restrict__ Wc,
                                                        const float* __restrict__ bc,
                                                        u16* __restrict__ uc) {
  const int id = blockIdx.x * 256 + threadIdx.x;  // 2*2048*2048 = 2^23
  const int d = id & (DI - 1);
  const int t = (id >> 11) & (LS - 1);
  const int b = id >> 22;
  const size_t rowb = (size_t)b * LS;
  const float4 w = *reinterpret_cast<const float4*>(&Wc[d * 4]);
  const float wv[4] = {w.x, w.y, w.z, w.w};
  float s = bc[d];
#pragma unroll
  for (int k = 0; k < 4; ++k) {
    const int tt = t - 3 + k;
    if (tt >= 0) s += bf2f(xz[(rowb + tt) * (2 * DI) + d]) * wv[k];
  }
  const float sl = s / (1.f + __expf(-s));
  uc[(rowb + t) * DI + d] = f2bf(sl);
}

// ---------------- chunked selective scan ----------------
// gid -> ng = gid&3 (4 states); ch2 = gid>>2: d = ch2&2047, c = (ch2>>11)&31, b = ch2>>16.
// Grid: B*NCH*DI*4/256 = 2048 blocks.

// Phase 1: local scan from h=0; emit S (final local state) and P = exp(A*sum_dt).
// Software-pipelined: t+1 operands loaded before computing t.
__global__ __launch_bounds__(256) void scan_phase1(const float* __restrict__ dtf,
                                                   const float* __restrict__ xdbl,
                                                   const u16* __restrict__ uc,
                                                   const float* __restrict__ Alog,
                                                   float* __restrict__ P,
                                                   float* __restrict__ S) {
  const int gid = blockIdx.x * 256 + threadIdx.x;
  const int ng = gid & 3;
  const int ch2 = gid >> 2;
  const int d = ch2 & (DI - 1);
  const int c = (ch2 >> 11) & (NCH - 1);
  const int b = ch2 >> 16;
  const float4 Alv = *reinterpret_cast<const float4*>(&Alog[d * DSn + ng * 4]);
  float Ar[4] = {-__expf(Alv.x), -__expf(Alv.y), -__expf(Alv.z), -__expf(Alv.w)};
  float h0 = 0.f, h1 = 0.f, h2 = 0.f, h3 = 0.f, sdt = 0.f;
  const size_t tbase = (size_t)b * LS + c * CL;
  const float* dtp = dtf + tbase * DI + d;
  const u16* ucp = uc + tbase * DI + d;
  const float* xd = xdbl + tbase * 96 + DTRk + ng * 4;

  float dtv = dtp[0];
  float uv = bf2f(ucp[0]);
  float4 Bv = *reinterpret_cast<const float4*>(&xd[0]);
  for (int t = 0; t < CL; ++t) {
    const int tn = (t < CL - 1) ? t + 1 : t;
    const float dtn = dtp[(size_t)tn * DI];
    const float un = bf2f(ucp[(size_t)tn * DI]);
    const float4 Bn = *reinterpret_cast<const float4*>(&xd[tn * 96]);
    const float du = dtv * uv;
    sdt += dtv;
    h0 = __expf(dtv * Ar[0]) * h0 + du * Bv.x;
    h1 = __expf(dtv * Ar[1]) * h1 + du * Bv.y;
    h2 = __expf(dtv * Ar[2]) * h2 + du * Bv.z;
    h3 = __expf(dtv * Ar[3]) * h3 + du * Bv.w;
    dtv = dtn; uv = un; Bv = Bn;
  }
  const size_t oi = (((size_t)b * NCH + c) * DI + d) * DSn + ng * 4;
  float4 Sv = {h0, h1, h2, h3};
  float4 Pv = {__expf(Ar[0] * sdt), __expf(Ar[1] * sdt), __expf(Ar[2] * sdt), __expf(Ar[3] * sdt)};
  *reinterpret_cast<float4*>(&S[oi]) = Sv;
  *reinterpret_cast<float4*>(&P[oi]) = Pv;
}

// Phase 3: compose incoming state from preceding chunks' (P,S), then re-scan
// the chunk computing y, add D*u, gate with silu(z), store bf16 y. Pipelined.
__global__ __launch_bounds__(256) void scan_phase3(const float* __restrict__ dtf,
                                                   const float* __restrict__ xdbl,
                                                   const u16* __restrict__ uc,
                                                   const u16* __restrict__ xz,
                                                   const float* __restrict__ Alog,
                                                   const float* __restrict__ Dp,
                                                   const float* __restrict__ P,
                                                   const float* __restrict__ S,
                                                   u16* __restrict__ yb) {
  const int gid = blockIdx.x * 256 + threadIdx.x;
  const int ng = gid & 3;
  const int ch2 = gid >> 2;
  const int d = ch2 & (DI - 1);
  const int c = (ch2 >> 11) & (NCH - 1);
  const int b = ch2 >> 16;
  const float4 Alv = *reinterpret_cast<const float4*>(&Alog[d * DSn + ng * 4]);
  float Ar[4] = {-__expf(Alv.x), -__expf(Alv.y), -__expf(Alv.z), -__expf(Alv.w)};
  const float Dd = Dp[d];
  // compose h_in from chunks 0..c-1
  float h0 = 0.f, h1 = 0.f, h2 = 0.f, h3 = 0.f;
  for (int cc = 0; cc < c; ++cc) {
    const size_t oi = (((size_t)b * NCH + cc) * DI + d) * DSn + ng * 4;
    const float4 Pv = *reinterpret_cast<const float4*>(&P[oi]);
    const float4 Sv = *reinterpret_cast<const float4*>(&S[oi]);
    h0 = Sv.x + Pv.x * h0;
    h1 = Sv.y + Pv.y * h1;
    h2 = Sv.z + Pv.z * h2;
    h3 = Sv.w + Pv.w * h3;
  }
  const size_t tbase = (size_t)b * LS + c * CL;
  const float* dtp = dtf + tbase * DI + d;
  const u16* ucp = uc + tbase * DI + d;
  const u16* zp = xz + tbase * (2 * DI) + DI + d;
  const float* xd = xdbl + tbase * 96 + DTRk + ng * 4;
  u16* yp = yb + tbase * DI + d;

  float dtv = dtp[0];
  float uv = bf2f(ucp[0]);
  float4 Bv = *reinterpret_cast<const float4*>(&xd[0]);
  float4 Cv = *reinterpret_cast<const float4*>(&xd[DSn]);
  u16 zr = zp[0];
  for (int t = 0; t < CL; ++t) {
    const int tn = (t < CL - 1) ? t + 1 : t;
    const float dtn = dtp[(size_t)tn * DI];
    const float un = bf2f(ucp[(size_t)tn * DI]);
    const float4 Bn = *reinterpret_cast<const float4*>(&xd[tn * 96]);
    const float4 Cn = *reinterpret_cast<const float4*>(&xd[tn * 96 + DSn]);
    const u16 zn = zp[(size_t)tn * (2 * DI)];
    const float du = dtv * uv;
    h0 = __expf(dtv * Ar[0]) * h0 + du * Bv.x;
    h1 = __expf(dtv * Ar[1]) * h1 + du * Bv.y;
    h2 = __expf(dtv * Ar[2]) * h2 + du * Bv.z;
    h3 = __expf(dtv * Ar[3]) * h3 + du * Bv.w;
    float y = h0 * Cv.x + h1 * Cv.y + h2 * Cv.z + h3 * Cv.w;
    y += __shfl_xor(y, 1);
    y += __shfl_xor(y, 2);
    if (ng == 0) {
      const float z = bf2f(zr);
      const float sz = z / (1.f + __expf(-z));
      const float yg = (y + uv * Dd) * sz;
      yp[(size_t)t * DI] = f2bf(yg);
    }
    dtv = dtn; uv = un; Bv = Bn; Cv = Cn; zr = zn;
  }
}

extern "C" void kernel_launch(void* const* d_in, const int* in_sizes, int n_in,
                              void* d_out, int out_size, void* d_ws, size_t ws_size,
                              hipStream_t stream) {
  (void)in_sizes; (void)n_in; (void)out_size; (void)ws_size;
  const float* x      = (const float*)d_in[0];
  const float* norm_w = (const float*)d_in[1];
  const float* W_in   = (const float*)d_in[2];
  const float* W_conv = (const float*)d_in[3];
  const float* b_conv = (const float*)d_in[4];
  const float* W_xp   = (const float*)d_in[5];
  const float* W_dt   = (const float*)d_in[6];
  const float* b_dt   = (const float*)d_in[7];
  const float* A_log  = (const float*)d_in[8];
  const float* Dvec   = (const float*)d_in[9];
  const float* W_out  = (const float*)d_in[10];
  float* out = (float*)d_out;

  char* ws = (char*)d_ws;
  size_t off = 0;
  auto alloc = [&](size_t bytes) -> void* {
    void* p = ws + off;
    off += (bytes + 255) & ~(size_t)255;
    return p;
  };
  u16* Win_b  = (u16*)alloc((size_t)4096 * 1024 * 2);   // 8 MB (dead after gemm<0>)
  u16* Wout_b = (u16*)alloc((size_t)1024 * 2048 * 2);
  u16* Wxp_b  = (u16*)alloc((size_t)128 * 2048 * 2);
  u16* Wdt_b  = (u16*)alloc((size_t)2048 * 64 * 2);
  u16* xn_b   = (u16*)alloc((size_t)MR * DM * 2);       // 8 MB (dead after gemm<0>)
  u16* xz_b   = (u16*)alloc((size_t)MR * 2 * DI * 2);
  u16* uc_b   = (u16*)alloc((size_t)MR * DI * 2);
  float* xdbl = (float*)alloc((size_t)MR * 96 * 4);
  u16* dtr_b  = (u16*)alloc((size_t)MR * 64 * 2);
  float* dtf  = (float*)alloc((size_t)MR * DI * 4);
  u16* y_b    = (u16*)alloc((size_t)MR * DI * 2);
  // Aliased scratch (regions dead at time of use):
  // gemm1 partials: Win_b (kp 0..3) + xn_b (kp 4..7), each 4 x 2MB = 8MB, consumed by
  // xproj_reduce before gemm<2>. P,S then alias the same regions for the scan.
  float* part0 = (float*)Win_b;
  float* part1 = (float*)xn_b;
  float* Pbuf = (float*)Win_b;
  float* Sbuf = (float*)xn_b;

  cvt_bf16_kernel<<<2048, 256, 0, stream>>>(W_in, Win_b, 4096 * 1024);
  cvt_bf16_kernel<<<2048, 256, 0, stream>>>(W_out, Wout_b, 1024 * 2048);
  cvt_bf16_kernel<<<512, 256, 0, stream>>>(W_dt, Wdt_b, 2048 * 64);
  cvt_pad_xproj_kernel<<<1024, 256, 0, stream>>>(W_xp, Wxp_b);

  rmsnorm_kernel<<<MR, 256, 0, stream>>>(x, norm_w, xn_b);

  // xz = xn @ W_in^T : [4096,4096]
  gemm_bt<0><<<dim3(32, 32), 256, 0, stream>>>(xn_b, Win_b, MR, 4096, 1024,
                                               nullptr, xz_b, nullptr, nullptr);
  // depthwise conv + silu -> u_conv
  conv_silu_kernel<<<32768, 256, 0, stream>>>(xz_b, W_conv, b_conv, uc_b);
  // x_dbl = u_conv @ W_xproj^T : [4096,96] via split-K(8) + reduce
  gemm_xproj_splitk<<<dim3(8, 32), 256, 0, stream>>>(uc_b, Wxp_b, part0, part1);
  xproj_reduce<<<2048, 256, 0, stream>>>(part0, part1, xdbl, dtr_b);
  // dt = softplus(dtr @ W_dt^T + b_dt) : [4096,2048]
  gemm_bt<2><<<dim3(16, 32), 256, 0, stream>>>(dtr_b, Wdt_b, MR, 2048, 64,
                                               dtf, nullptr, b_dt, nullptr);
  // chunked selective scan (phase1: local scans; phase3: compose + rescan + gate)
  scan_phase1<<<2048, 256, 0, stream>>>(dtf, xdbl, uc_b, A_log, Pbuf, Sbuf);
  scan_phase3<<<2048, 256, 0, stream>>>(dtf, xdbl, uc_b, xz_b, A_log, Dvec,
                                        Pbuf, Sbuf, y_b);
  // out = y @ W_out^T + x
  gemm_bt<3><<<dim3(8, 32), 256, 0, stream>>>(y_b, Wout_b, MR, 1024, 2048,
                                              out, nullptr, nullptr, x);
}